// Round 7
// baseline (185.535 us; speedup 1.0000x reference)
//
#include <hip/hip_runtime.h>
#include <hip/hip_fp16.h>

#define NB 64
#define NBUCKETS (NB * NB)   // 4096

typedef unsigned int uint2v __attribute__((ext_vector_type(2)));
typedef unsigned int uint4v __attribute__((ext_vector_type(4)));

__device__ __forceinline__ float sigm(float v)
{
    return 1.0f / (1.0f + __expf(0.3f - v));
}

__device__ __forceinline__ float2 unpack_h2(unsigned int w)
{
    __half2 h = *reinterpret_cast<__half2*>(&w);
    return make_float2(__low2float(h), __high2float(h));
}

// ---------------------------------------------------------------------------
// Phase 1a (Q8 path): sigmoid + transpose + (y,z)-quad pack.
// Q[z][y][x] (x fastest) is 8B: dword0 = half2(s(x,y,z),   s(x,y+1,z))
//                               dword1 = half2(s(x,y,z+1), s(x,y+1,z+1))
// y==255 -> high halves 0; z==255 -> dword1 = 0.  One dwordx4 at (z,y,x)
// gives all 8 trilinear corners for (x..x+1, y..y+1, z..z+1).
// Block: (32x, 32z) tile x 8 y-planes, carrying plane y+1; z+1 via 33-wide
// LDS plane. Grid: 32 ygroups * 8 xt * 8 zt = 2048 blocks.
// ---------------------------------------------------------------------------
__global__ __launch_bounds__(256) void packq_kernel(
    const float* __restrict__ dens, uint2v* __restrict__ Q)
{
    __shared__ float S[2][33 * 33 + 1];
    int bid = blockIdx.x;
    int y0 = (bid & 31) * 8;
    int xt = ((bid >> 5) & 7) * 32;
    int zt = (bid >> 8) * 32;
    int tid = threadIdx.x;

    // load plane y (33 z-cols x 32 x-rows) into S[y&1]; zeros where OOB
    auto load_plane = [&](int y) {
        float* Sp = S[y & 1];
        #pragma unroll
        for (int r = 0; r < 5; ++r) {
            int li = r * 256 + tid;
            if (li < 33 * 32) {
                int zc = li % 33, xr = li / 33;
                int zz = zt + zc;
                float v = 0.0f;
                if (zz < 256 && y < 256)
                    v = sigm(dens[(size_t)(xt + xr) * 65536 +
                                  (size_t)y * 256 + zz]);
                Sp[zc * 33 + xr] = v;
            }
        }
    };

    load_plane(y0 + 8);
    for (int y = y0 + 7; y >= y0; --y) {
        __syncthreads();
        load_plane(y);
        __syncthreads();
        const float* S0 = S[y & 1];         // plane y
        const float* S1 = S[(y + 1) & 1];   // plane y+1
        int xo = tid & 31;
        int zb = tid >> 5;                  // 0..7
        #pragma unroll
        for (int i = 0; i < 4; ++i) {
            int zo = zb + 8 * i;
            __half2 d0 = __floats2half2_rn(S0[zo * 33 + xo],
                                           S1[zo * 33 + xo]);
            __half2 d1 = __floats2half2_rn(S0[(zo + 1) * 33 + xo],
                                           S1[(zo + 1) * 33 + xo]);
            uint2v q;
            q.x = *reinterpret_cast<unsigned int*>(&d0);
            q.y = *reinterpret_cast<unsigned int*>(&d1);
            Q[((zt + zo) << 16) | (y << 8) | (xt + xo)] = q;
        }
    }
}

// ---------------------------------------------------------------------------
// Phase 1b (fallback path): sigmoid + transpose + y-pair pack (4B/voxel).
// ---------------------------------------------------------------------------
__global__ __launch_bounds__(256) void pack_kernel(
    const float* __restrict__ dens, unsigned int* __restrict__ P)
{
    __shared__ float tile[32][33];
    int bid = blockIdx.x;
    int y0 = (bid & 31) * 8;
    int xt = ((bid >> 5) & 7) * 32;
    int zt = (bid >> 8) * 32;
    int tz = threadIdx.x & 31;
    int tr = threadIdx.x >> 5;

    float prev[4];
    int ytop = y0 + 8;
    if (ytop < 256) {
        #pragma unroll
        for (int i = 0; i < 4; ++i) {
            int xr = tr + 8 * i;
            tile[xr][tz] = sigm(dens[(size_t)(xt + xr) * 65536 +
                                     (size_t)ytop * 256 + (zt + tz)]);
        }
        __syncthreads();
        #pragma unroll
        for (int i = 0; i < 4; ++i)
            prev[i] = tile[tz][tr + 8 * i];
        __syncthreads();
    } else {
        #pragma unroll
        for (int i = 0; i < 4; ++i) prev[i] = 0.0f;
    }

    for (int yy = 7; yy >= 0; --yy) {
        int y = y0 + yy;
        #pragma unroll
        for (int i = 0; i < 4; ++i) {
            int xr = tr + 8 * i;
            tile[xr][tz] = sigm(dens[(size_t)(xt + xr) * 65536 +
                                     (size_t)y * 256 + (zt + tz)]);
        }
        __syncthreads();
        #pragma unroll
        for (int i = 0; i < 4; ++i) {
            int zr = tr + 8 * i;
            float cur = tile[tz][zr];
            __half2 h = __floats2half2_rn(cur, prev[i]);
            P[((zt + zr) << 16) | (y << 8) | (xt + tz)] =
                *reinterpret_cast<unsigned int*>(&h);
            prev[i] = cur;
        }
        __syncthreads();
    }
}

// ---------------------------------------------------------------------------
// Ray bucketing: Morton-interleaved 64x64 grid over detector (ty, tz)
// ---------------------------------------------------------------------------
__device__ __forceinline__ int ray_bucket(const float* __restrict__ target, int r)
{
    float ty = target[3 * r + 1];
    float tz = target[3 * r + 2];
    int bu = (int)((ty + 10.0f) * (NB / 260.0f));
    int bv = (int)((tz + 10.0f) * (NB / 260.0f));
    bu = min(max(bu, 0), NB - 1);
    bv = min(max(bv, 0), NB - 1);
    int m = 0;
    #pragma unroll
    for (int b = 0; b < 6; ++b)
        m |= (((bu >> b) & 1) << (2 * b)) | (((bv >> b) & 1) << (2 * b + 1));
    return m;
}

__global__ __launch_bounds__(256) void zero_kernel(int* __restrict__ p, int n)
{
    int i = blockIdx.x * 256 + threadIdx.x;
    if (i < n) p[i] = 0;
}

__global__ __launch_bounds__(256) void hist_kernel(
    const float* __restrict__ target, int* __restrict__ hist, int nrays)
{
    int r = blockIdx.x * 256 + threadIdx.x;
    if (r < nrays) atomicAdd(&hist[ray_bucket(target, r)], 1);
}

// single block, 256 threads, 16 buckets each: exclusive scan + cursor zero
__global__ __launch_bounds__(256) void scan_kernel(
    const int* __restrict__ hist, int* __restrict__ offs, int* __restrict__ cursor)
{
    __shared__ int part[256];
    int t = threadIdx.x;
    int v[16];
    int s = 0;
    #pragma unroll
    for (int i = 0; i < 16; ++i) {
        v[i] = hist[t * 16 + i];
        s += v[i];
    }
    part[t] = s;
    __syncthreads();
    for (int d = 1; d < 256; d <<= 1) {
        int add = (t >= d) ? part[t - d] : 0;
        __syncthreads();
        part[t] += add;
        __syncthreads();
    }
    int base = part[t] - s;
    #pragma unroll
    for (int i = 0; i < 16; ++i) {
        offs[t * 16 + i] = base;
        base += v[i];
        cursor[t * 16 + i] = 0;
    }
}

__global__ __launch_bounds__(256) void scatter_kernel(
    const float* __restrict__ target, const int* __restrict__ offs,
    int* __restrict__ cursor, int* __restrict__ perm, int nrays)
{
    int r = blockIdx.x * 256 + threadIdx.x;
    if (r >= nrays) return;
    int bkt = ray_bucket(target, r);
    int pos = offs[bkt] + atomicAdd(&cursor[bkt], 1);
    perm[pos] = r;
}

// ---------------------------------------------------------------------------
// Boundary fetches
// ---------------------------------------------------------------------------
// Q8: all 4 corners at one x: (c[y,z], c[y+1,z], c[y,z+1], c[y+1,z+1])
__device__ __forceinline__ float4 fetchQ4(
    const uint2v* __restrict__ Q, int x, int y, int z)
{
    if ((unsigned)x < 256u) {
        if ((unsigned)y < 256u) {
            if ((unsigned)z < 256u) {
                uint2v q = Q[(z << 16) | (y << 8) | x];
                float2 a = unpack_h2(q.x), b = unpack_h2(q.y);
                return make_float4(a.x, a.y, b.x, b.y);
            }
            if (z == -1) {
                uint2v q = Q[(y << 8) | x];
                float2 a = unpack_h2(q.x);
                return make_float4(0.0f, 0.0f, a.x, a.y);
            }
        } else if (y == -1) {
            if ((unsigned)z < 256u) {
                uint2v q = Q[(z << 16) | x];
                float2 a = unpack_h2(q.x), b = unpack_h2(q.y);
                return make_float4(0.0f, a.x, 0.0f, b.x);
            }
            if (z == -1) {
                uint2v q = Q[x];
                float2 a = unpack_h2(q.x);
                return make_float4(0.0f, 0.0f, 0.0f, a.x);
            }
        }
    }
    return make_float4(0.0f, 0.0f, 0.0f, 0.0f);
}

// 4B path: (y, y+1) pair at one (x, z)
__device__ __forceinline__ float2 fetchP(
    const unsigned int* __restrict__ P, int x, int y, int z)
{
    if ((unsigned)x < 256u && (unsigned)z < 256u) {
        if ((unsigned)y < 256u)
            return unpack_h2(P[(z << 16) | (y << 8) | x]);
        if (y == -1) {
            float2 v = unpack_h2(P[(z << 16) | x]);
            return make_float2(0.0f, v.x);
        }
    }
    return make_float2(0.0f, 0.0f);
}

// ---------------------------------------------------------------------------
// Phase 2: ray-packeted marching.
// Q8=true : 8 rays x 8 samples per wave, ONE dwordx4 gather per sample.
// Q8=false: 4 rays x 16 samples per wave, two dwordx2 gathers per sample.
// ---------------------------------------------------------------------------
template <bool Q8>
__global__ __launch_bounds__(256) void drr_kernel(
    const void*   __restrict__ volp,
    const float*  __restrict__ source,
    const float*  __restrict__ target,
    const float*  __restrict__ affine,
    const int*    __restrict__ npts_ptr,
    const int*    __restrict__ perm,
    float*        __restrict__ out,
    int nrays)
{
    constexpr int R  = Q8 ? 8 : 4;      // rays per wave
    constexpr int PH = 64 / R;          // sample phases per ray

    const int lane  = threadIdx.x & 63;
    const int sub   = lane / PH;
    const int phase = lane % PH;
    const int wave  = threadIdx.x >> 6;
    int slot = blockIdx.x * (4 * R) + wave * R + sub;
    bool valid = (slot < nrays);
    if (slot >= nrays) slot = nrays - 1;
    const int ray = perm ? perm[slot] : slot;
    const int npts = *npts_ptr;

    // inverse affine (last row [0,0,0,1])
    float a00 = affine[0], a01 = affine[1], a02 = affine[2],  b0 = affine[3];
    float a10 = affine[4], a11 = affine[5], a12 = affine[6],  b1 = affine[7];
    float a20 = affine[8], a21 = affine[9], a22 = affine[10], b2 = affine[11];
    float det = a00 * (a11 * a22 - a12 * a21)
              - a01 * (a10 * a22 - a12 * a20)
              + a02 * (a10 * a21 - a11 * a20);
    float rdet = 1.0f / det;
    float i00 =  (a11 * a22 - a12 * a21) * rdet;
    float i01 = -(a01 * a22 - a02 * a21) * rdet;
    float i02 =  (a01 * a12 - a02 * a11) * rdet;
    float i10 = -(a10 * a22 - a12 * a20) * rdet;
    float i11 =  (a00 * a22 - a02 * a20) * rdet;
    float i12 = -(a00 * a12 - a02 * a10) * rdet;
    float i20 =  (a10 * a21 - a11 * a20) * rdet;
    float i21 = -(a00 * a21 - a01 * a20) * rdet;
    float i22 =  (a00 * a11 - a01 * a10) * rdet;
    float it0 = -(i00 * b0 + i01 * b1 + i02 * b2);
    float it1 = -(i10 * b0 + i11 * b1 + i12 * b2);
    float it2 = -(i20 * b0 + i21 * b1 + i22 * b2);

    float sx = source[3 * ray + 0], sy = source[3 * ray + 1], sz = source[3 * ray + 2];
    float tx = target[3 * ray + 0], ty = target[3 * ray + 1], tz = target[3 * ray + 2];
    float dwx = tx - sx, dwy = ty - sy, dwz = tz - sz;
    float rl = sqrtf(dwx * dwx + dwy * dwy + dwz * dwz);

    float vsx = i00 * sx + i01 * sy + i02 * sz + it0;
    float vsy = i10 * sx + i11 * sy + i12 * sz + it1;
    float vsz = i20 * sx + i21 * sy + i22 * sz + it2;
    float vtx = i00 * tx + i01 * ty + i02 * tz + it0;
    float vty = i10 * tx + i11 * ty + i12 * tz + it1;
    float vtz = i20 * tx + i21 * ty + i22 * tz + it2;
    float vdx = vtx - vsx, vdy = vty - vsy, vdz = vtz - vsz;

    // clip to alpha range where a sample can touch an in-bounds corner
    float lo = 0.0f, hi = 1.0f;
    {
        float s3v[3] = {vsx, vsy, vsz};
        float d3v[3] = {vdx, vdy, vdz};
        #pragma unroll
        for (int k = 0; k < 3; ++k) {
            if (fabsf(d3v[k]) > 1e-8f) {
                float a = (-1.0f - s3v[k]) / d3v[k];
                float b = (256.0f - s3v[k]) / d3v[k];
                lo = fmaxf(lo, fminf(a, b));
                hi = fminf(hi, fmaxf(a, b));
            } else if (s3v[k] <= -1.0f || s3v[k] >= 256.0f) {
                lo = 1.0f; hi = 0.0f;
            }
        }
    }
    const float stepN = (float)(npts > 1 ? npts - 1 : 1);
    int pstart = max(0, (int)floorf(lo * stepN) - 1);
    int pend   = min(npts - 1, (int)ceilf(hi * stepN) + 1);

    const float step = 1.0f / stepN;
    float acc = 0.0f;

    const uint2v*       Q  = (const uint2v*)volp;
    const unsigned int* P  = (const unsigned int*)volp;

    float al0 = (float)(pstart + phase) * step;
    float x = fmaf(al0, vdx, vsx);
    float y = fmaf(al0, vdy, vsy);
    float z = fmaf(al0, vdz, vsz);
    float dSx = (float)PH * step * vdx;
    float dSy = (float)PH * step * vdy;
    float dSz = (float)PH * step * vdz;

    #pragma unroll 4
    for (int p = pstart + phase; p <= pend; p += PH) {
        float fx = floorf(x), fy = floorf(y), fz = floorf(z);
        int ix = (int)fx, iy = (int)fy, iz = (int)fz;
        float wx = x - fx, wy = y - fy, wz = z - fz;
        x += dSx; y += dSy; z += dSz;

        float2 pa, pb, pc, pd;  // (y,y+1) pairs at (x,z),(x,z+1),(x+1,z),(x+1,z+1)
        if (Q8) {
            bool interior = ((unsigned)ix < 255u) & ((unsigned)iy < 256u) &
                            ((unsigned)iz < 256u);
            if (interior) {
                int idx = (iz << 16) | (iy << 8) | ix;
                const unsigned int* qp =
                    (const unsigned int*)Q + ((size_t)idx << 1);
                uint4v v;
                __builtin_memcpy(&v, qp, 16);
                pa = unpack_h2(v.x);          // (y,y+1) @ (x,   z)
                pb = unpack_h2(v.y);          // (y,y+1) @ (x,   z+1)
                pc = unpack_h2(v.z);          // (y,y+1) @ (x+1, z)
                pd = unpack_h2(v.w);          // (y,y+1) @ (x+1, z+1)
            } else {
                float4 fa = fetchQ4(Q, ix,     iy, iz);
                float4 fb = fetchQ4(Q, ix + 1, iy, iz);
                pa = make_float2(fa.x, fa.y);
                pb = make_float2(fa.z, fa.w);
                pc = make_float2(fb.x, fb.y);
                pd = make_float2(fb.z, fb.w);
            }
        } else {
            bool interior = ((unsigned)ix < 255u) & ((unsigned)iy < 256u) &
                            ((unsigned)iz < 255u);
            if (interior) {
                int idx = (iz << 16) | (iy << 8) | ix;
                uint2v va, vb;
                __builtin_memcpy(&va, P + idx, 8);
                __builtin_memcpy(&vb, P + idx + 65536, 8);
                pa = unpack_h2(va.x);
                pc = unpack_h2(va.y);
                pb = unpack_h2(vb.x);
                pd = unpack_h2(vb.y);
            } else {
                pa = fetchP(P, ix,     iy, iz);
                pc = fetchP(P, ix + 1, iy, iz);
                pb = fetchP(P, ix,     iy, iz + 1);
                pd = fetchP(P, ix + 1, iy, iz + 1);
            }
        }
        float ca = pa.x + wy * (pa.y - pa.x);   // (x,   z)
        float cb = pb.x + wy * (pb.y - pb.x);   // (x,   z+1)
        float cc = pc.x + wy * (pc.y - pc.x);   // (x+1, z)
        float cd = pd.x + wy * (pd.y - pd.x);   // (x+1, z+1)
        float e = ca + wz * (cb - ca);          // x
        float f = cc + wz * (cd - cc);          // x+1
        acc += e + wx * (f - e);
    }

    // segmented PH-lane reduction (R rays per wave)
    #pragma unroll
    for (int off = PH / 2; off > 0; off >>= 1)
        acc += __shfl_down(acc, off, PH);

    if (phase == 0 && valid)
        out[ray] = acc * rl / (float)npts;
}

// ---------------------------------------------------------------------------
extern "C" void kernel_launch(void* const* d_in, const int* in_sizes, int n_in,
                              void* d_out, int out_size, void* d_ws, size_t ws_size,
                              hipStream_t stream)
{
    const float* dens   = (const float*)d_in[0];
    const float* source = (const float*)d_in[1];
    const float* target = (const float*)d_in[2];
    const float* affine = (const float*)d_in[3];
    const int*   npts   = (const int*)d_in[4];
    float* out = (float*)d_out;

    const int nvox  = in_sizes[0];          // 256^3
    const int nrays = in_sizes[1] / 3;      // B*N

    size_t qBytes    = ((size_t)nvox * 8 + 255) & ~(size_t)255;
    size_t pBytes    = ((size_t)nvox * 4 + 255) & ~(size_t)255;
    size_t sortBytes = (size_t)(3 * NBUCKETS + nrays) * sizeof(int);

    const bool q8 = (ws_size >= qBytes + sortBytes);
    size_t volBytes = q8 ? qBytes : pBytes;

    int* hist   = (int*)((char*)d_ws + volBytes);
    int* offs   = hist + NBUCKETS;
    int* cursor = offs + NBUCKETS;
    int* perm   = cursor + NBUCKETS;
    const bool srt = (ws_size >= volBytes + sortBytes);
    int* permArg = srt ? perm : nullptr;

    if (srt) {
        zero_kernel<<<(NBUCKETS + 255) / 256, 256, 0, stream>>>(hist, NBUCKETS);
        hist_kernel<<<(nrays + 255) / 256, 256, 0, stream>>>(target, hist, nrays);
        scan_kernel<<<1, 256, 0, stream>>>(hist, offs, cursor);
        scatter_kernel<<<(nrays + 255) / 256, 256, 0, stream>>>(target, offs, cursor, perm, nrays);
    }

    if (q8) {
        uint2v* Q = (uint2v*)d_ws;
        packq_kernel<<<2048, 256, 0, stream>>>(dens, Q);
        // 32 rays per block (4 waves x 8 rays)
        drr_kernel<true><<<(nrays + 31) / 32, 256, 0, stream>>>(
            Q, source, target, affine, npts, permArg, out, nrays);
    } else {
        unsigned int* P = (unsigned int*)d_ws;
        pack_kernel<<<2048, 256, 0, stream>>>(dens, P);
        // 16 rays per block (4 waves x 4 rays)
        drr_kernel<false><<<(nrays + 15) / 16, 256, 0, stream>>>(
            P, source, target, affine, npts, permArg, out, nrays);
    }
}